// Round 2
// baseline (2424.733 us; speedup 1.0000x reference)
//
#include <hip/hip_runtime.h>
#include <stdint.h>

// Problem constants (EdgeEncoder_28071906247258)
#define BB 4
#define NN 100000
#define DD 128
#define EE 262144   // 2^18 edges per batch
#define HH 128
#define OO 128

typedef __attribute__((ext_vector_type(4))) float f32x4;
typedef __attribute__((ext_vector_type(8))) __bf16 bf16x8;
typedef __attribute__((ext_vector_type(8))) unsigned short u16x8;

static __device__ __forceinline__ unsigned short f2bf(float f) {
    union { float f; unsigned u; } v; v.f = f;
    return (unsigned short)((v.u + 0x7fffu + ((v.u >> 16) & 1u)) >> 16);  // RNE
}

// ---------------------------------------------------------------------------
// Prep: swizzle W1 rows 0..255 (fp32 [257][128]) into bf16 B-fragment order:
//   frag(kt,nt): lane holds W[k = kt*32 + (lane>>4)*8 + j][n = nt*16 + (lane&15)]
//   flat ushort index = ((kt*8+nt)*64 + lane)*8 + j
// ---------------------------------------------------------------------------
__global__ __launch_bounds__(256) void prep_w1(const float* __restrict__ W1,
                                               unsigned short* __restrict__ w1f) {
    int t = blockIdx.x * 256 + threadIdx.x;          // grid exact: 128*256 = 32768
    int k = t >> 7, n = t & 127;
    int f = ((((k >> 5) * 8 + (n >> 4)) * 64) + ((k >> 3) & 3) * 16 + (n & 15)) * 8 + (k & 7);
    w1f[f] = f2bf(W1[t]);
}

// W2 fragments with permuted k-axis: k2 = (k&15)*8 + (k>>4). The h-tile is
// stored in the same permuted order, so layer 2 computes the identical dot
// product with contiguous-per-lane LDS writes (ds_write_b128).
__global__ __launch_bounds__(256) void prep_w2(const float* __restrict__ W2,
                                               unsigned short* __restrict__ w2f) {
    int t = blockIdx.x * 256 + threadIdx.x;          // grid exact: 64*256 = 16384
    int k = t >> 7, n = t & 127;
    int k2 = (k & 15) * 8 + (k >> 4);
    int f = ((((k2 >> 5) * 8 + (n >> 4)) * 64) + ((k2 >> 3) & 3) * 16 + (n & 15)) * 8 + (k2 & 7);
    w2f[f] = f2bf(W2[t]);
}

// node_emb fp32 -> bf16 (same RNE conversion the hot loop used to do per-gather)
__global__ __launch_bounds__(256) void prep_node(const float* __restrict__ ne,
                                                 unsigned short* __restrict__ nb) {
    size_t t = (size_t)blockIdx.x * 256 + threadIdx.x;   // grid exact: 25000*256 = 6.4M
    const f32x4* s = (const f32x4*)ne + (t << 1);
    f32x4 a = s[0], b = s[1];
    u16x8 o;
    o[0] = f2bf(a[0]); o[1] = f2bf(a[1]); o[2] = f2bf(a[2]); o[3] = f2bf(a[3]);
    o[4] = f2bf(b[0]); o[5] = f2bf(b[1]); o[6] = f2bf(b[2]); o[7] = f2bf(b[3]);
    *((u16x8*)nb + t) = o;
}

// ---------------------------------------------------------------------------
// Helpers for the fused edge MLP
// ---------------------------------------------------------------------------

// Load idx -> clamp -> gather 16 bf16x8 A-fragments for one 32-edge tile.
static __device__ __forceinline__ void gather_tile(
    const unsigned short* __restrict__ nb, const int* __restrict__ ei,
    int e0t, unsigned nbase, int nl, int quad, bf16x8* dst)
{
    unsigned ou[2], ov[2];
#pragma unroll
    for (int mt = 0; mt < 2; ++mt) {
        int e = e0t + mt * 16 + nl;
        int2 p = ((const int2*)ei)[e];
        int iu = min(max(p.x, 0), NN - 1);
        int iv = min(max(p.y, 0), NN - 1);
        ou[mt] = nbase + (unsigned)iu * DD + quad * 8;
        ov[mt] = nbase + (unsigned)iv * DD + quad * 8;
    }
#pragma unroll
    for (int kt = 0; kt < 8; ++kt)
#pragma unroll
        for (int mt = 0; mt < 2; ++mt)
            dst[kt * 2 + mt] = *(const bf16x8*)(nb + ((kt < 4) ? ou[mt] : ov[mt]) + (kt & 3) * 32);
}

static __device__ __forceinline__ void layer1(
    const bf16x8* af, const bf16x8* __restrict__ w1b, int lane, f32x4 acc[2][8])
{
#pragma unroll
    for (int mt = 0; mt < 2; ++mt)
#pragma unroll
        for (int nt = 0; nt < 8; ++nt)
            acc[mt][nt] = f32x4{0.f, 0.f, 0.f, 0.f};
#pragma unroll
    for (int kt = 0; kt < 8; ++kt) {
#pragma unroll
        for (int nt = 0; nt < 8; ++nt) {
            bf16x8 bf = w1b[(kt * 8 + nt) * 64 + lane];
            acc[0][nt] = __builtin_amdgcn_mfma_f32_16x16x32_bf16(af[kt * 2 + 0], bf, acc[0][nt], 0, 0, 0);
            acc[1][nt] = __builtin_amdgcn_mfma_f32_16x16x32_bf16(af[kt * 2 + 1], bf, acc[1][nt], 0, 0, 0);
        }
    }
}

// Epilogue-1 (bias+sel+relu, packed bf16 LDS write in permuted-k layout),
// per-wave LDS transpose, layer-2 MFMA, epilogue-2 store.
static __device__ __forceinline__ void finish_tile(
    f32x4 acc[2][8], const f32x4* sel, int eb,
    const float* b1v, const float* w1cv, const float* b2v,
    unsigned short* hw,                 // this wave's hst base: [2][16*136]
    const bf16x8* __restrict__ w2b,
    int lane, int nl, int quad, float* __restrict__ out)
{
#pragma unroll
    for (int q = 0; q < 2; ++q) {
#pragma unroll
        for (int i = 0; i < 4; ++i) {
            bf16x8 hv;
#pragma unroll
            for (int nt = 0; nt < 8; ++nt) {
                float h = acc[q][nt][i] + sel[q][i] * w1cv[nt] + b1v[nt];
                hv[nt] = (__bf16)fmaxf(h, 0.f);   // k' = nl*8 + nt (permuted axis)
            }
            *(bf16x8*)(hw + q * (16 * 136) + (quad * 4 + i) * 136 + nl * 8) = hv;
        }
    }

    f32x4 a2[2][8];
#pragma unroll
    for (int q = 0; q < 2; ++q)
#pragma unroll
        for (int nt = 0; nt < 8; ++nt)
            a2[q][nt] = f32x4{0.f, 0.f, 0.f, 0.f};

#pragma unroll
    for (int kt2 = 0; kt2 < 4; ++kt2) {
        bf16x8 h0 = *(const bf16x8*)(hw + nl * 136 + kt2 * 32 + quad * 8);
        bf16x8 h1 = *(const bf16x8*)(hw + 16 * 136 + nl * 136 + kt2 * 32 + quad * 8);
#pragma unroll
        for (int nt = 0; nt < 8; ++nt) {
            bf16x8 bf = w2b[(kt2 * 8 + nt) * 64 + lane];
            a2[0][nt] = __builtin_amdgcn_mfma_f32_16x16x32_bf16(h0, bf, a2[0][nt], 0, 0, 0);
            a2[1][nt] = __builtin_amdgcn_mfma_f32_16x16x32_bf16(h1, bf, a2[1][nt], 0, 0, 0);
        }
    }

#pragma unroll
    for (int q = 0; q < 2; ++q)
#pragma unroll
        for (int nt = 0; nt < 8; ++nt)
#pragma unroll
            for (int i = 0; i < 4; ++i) {
                float o = a2[q][nt][i] + b2v[nt];
                out[(size_t)(eb + q * 16 + quad * 4 + i) * OO + nt * 16 + nl] = fmaxf(o, 0.f);
            }
}

// ---------------------------------------------------------------------------
// Fused edge MLP. Block = 256 threads = 4 waves; each wave owns 4 tiles of
// 32 edges (128 edges), software-pipelined: while tile t runs epilogue1 +
// layer2, tile t+1's idx-load + gathers are in flight (double-buffered af).
// All LDS is per-wave private -> no __syncthreads.
//   BF16N : gather pre-converted bf16 node rows (main path, pipelined)
//   W2LDS : last-resort tiny-workspace path (stage W2 frags in LDS)
// ---------------------------------------------------------------------------
template<bool BF16N, bool W2LDS>
__global__ __launch_bounds__(256, BF16N ? 3 : 2) void edge_mlp(
    const float* __restrict__ node_emb,
    const unsigned short* __restrict__ node_bf,
    const int* __restrict__ edge_index,
    const float* __restrict__ edge_sel,
    const float* __restrict__ W1,
    const float* __restrict__ b1,
    const float* __restrict__ W2,
    const float* __restrict__ b2,
    const unsigned short* __restrict__ w1f,
    const unsigned short* __restrict__ w2f,
    float* __restrict__ out)
{
    __shared__ unsigned short hst[4][2][16 * 136];   // per-wave, per-q h tiles (34816 B)
    __shared__ unsigned short w2s[W2LDS ? 16384 : 1];

    const int tid = threadIdx.x;

    if constexpr (W2LDS) {
        for (int s = tid; s < 16384; s += 256) {
            int k = s >> 7, n = s & 127;
            int k2 = (k & 15) * 8 + (k >> 4);
            int f = ((((k2 >> 5) * 8 + (n >> 4)) * 64) + ((k2 >> 3) & 3) * 16 + (n & 15)) * 8 + (k2 & 7);
            w2s[f] = f2bf(W2[s]);
        }
        __syncthreads();
    }

    const int lane = tid & 63;
    const int wv = tid >> 6;
    const int nl = lane & 15;     // A-row lane / output-col lane
    const int quad = lane >> 4;   // 0..3

    // Per-lane epilogue constants: col = nt*16 + nl
    float b1v[8], w1cv[8], b2v[8];
#pragma unroll
    for (int nt = 0; nt < 8; ++nt) {
        b1v[nt] = b1[nt * 16 + nl];
        w1cv[nt] = W1[256 * 128 + nt * 16 + nl];  // W1 row 256 = sel weights
        b2v[nt] = b2[nt * 16 + nl];
    }

    // Wave's contiguous 128-edge chunk (aligned: never crosses a batch boundary)
    const int e0 = (blockIdx.x * 4 + wv) * 128;
    const unsigned nbase = (unsigned)(e0 >> 18) * (NN * DD);

    const bf16x8* w1b = (const bf16x8*)w1f;
    const bf16x8* w2b = (const bf16x8*)(W2LDS ? (const unsigned short*)w2s : w2f);
    unsigned short* hw = &hst[wv][0][0];

    if constexpr (BF16N) {
        bf16x8 afbuf[2][16];
        f32x4 selbuf[2][2];

        // Prologue: tile 0 in flight
        gather_tile(node_bf, edge_index, e0, nbase, nl, quad, afbuf[0]);
        selbuf[0][0] = *(const f32x4*)(edge_sel + e0 + quad * 4);
        selbuf[0][1] = *(const f32x4*)(edge_sel + e0 + 16 + quad * 4);

#pragma unroll
        for (int t = 0; t < 4; ++t) {
            const int eb = e0 + t * 32;
            f32x4 acc[2][8];
            layer1(afbuf[t & 1], w1b, lane, acc);

            if (t < 3) {   // prefetch next tile under epilogue1 + layer2 + store
                gather_tile(node_bf, edge_index, eb + 32, nbase, nl, quad, afbuf[(t + 1) & 1]);
                selbuf[(t + 1) & 1][0] = *(const f32x4*)(edge_sel + eb + 32 + quad * 4);
                selbuf[(t + 1) & 1][1] = *(const f32x4*)(edge_sel + eb + 48 + quad * 4);
            }

            finish_tile(acc, selbuf[t & 1], eb, b1v, w1cv, b2v, hw, w2b,
                        lane, nl, quad, out);
        }
    } else {
        // Fallback: fp32 gather + in-loop convert, non-pipelined
#pragma unroll
        for (int t = 0; t < 4; ++t) {
            const int eb = e0 + t * 32;
            unsigned ou[2], ov[2];
#pragma unroll
            for (int mt = 0; mt < 2; ++mt) {
                int e = eb + mt * 16 + nl;
                int2 p = ((const int2*)edge_index)[e];
                int iu = min(max(p.x, 0), NN - 1);
                int iv = min(max(p.y, 0), NN - 1);
                ou[mt] = nbase + (unsigned)iu * DD + quad * 8;
                ov[mt] = nbase + (unsigned)iv * DD + quad * 8;
            }
            bf16x8 af[16];
#pragma unroll
            for (int kt = 0; kt < 8; ++kt)
#pragma unroll
                for (int mt = 0; mt < 2; ++mt) {
                    unsigned o = ((kt < 4) ? ou[mt] : ov[mt]) + (kt & 3) * 32;
                    f32x4 x0 = *(const f32x4*)(node_emb + o);
                    f32x4 x1 = *(const f32x4*)(node_emb + o + 4);
                    bf16x8 a;
                    a[0] = (__bf16)x0[0]; a[1] = (__bf16)x0[1];
                    a[2] = (__bf16)x0[2]; a[3] = (__bf16)x0[3];
                    a[4] = (__bf16)x1[0]; a[5] = (__bf16)x1[1];
                    a[6] = (__bf16)x1[2]; a[7] = (__bf16)x1[3];
                    af[kt * 2 + mt] = a;
                }
            f32x4 sel[2];
            sel[0] = *(const f32x4*)(edge_sel + eb + quad * 4);
            sel[1] = *(const f32x4*)(edge_sel + eb + 16 + quad * 4);

            f32x4 acc[2][8];
            layer1(af, w1b, lane, acc);
            finish_tile(acc, sel, eb, b1v, w1cv, b2v, hw, w2b, lane, nl, quad, out);
        }
    }
}

extern "C" void kernel_launch(void* const* d_in, const int* in_sizes, int n_in,
                              void* d_out, int out_size, void* d_ws, size_t ws_size,
                              hipStream_t stream) {
    const float* node_emb  = (const float*)d_in[0];
    const int*   edge_index= (const int*)d_in[1];
    const float* edge_sel  = (const float*)d_in[2];
    const float* W1        = (const float*)d_in[3];
    const float* b1        = (const float*)d_in[4];
    const float* W2        = (const float*)d_in[5];
    const float* b2        = (const float*)d_in[6];
    float* out             = (float*)d_out;

    unsigned short* w1f = (unsigned short*)d_ws;              // 64 KB
    const size_t NODE_BYTES = (size_t)BB * NN * DD * 2;       // 102,400,000 B
    const size_t NEED_B = 65536 + 32768;                      // w1f + w2f
    const size_t NEED_A = NEED_B + NODE_BYTES;

    prep_w1<<<dim3(128), dim3(256), 0, stream>>>(W1, w1f);

    // 2048 blocks * 4 waves * 128 edges = 1,048,576 edges, exact
    if (ws_size >= NEED_A) {
        unsigned short* w2f = w1f + 32768;       // byte offset 65536
        unsigned short* nbf = w2f + 16384;       // byte offset 98304 (16B aligned)
        prep_w2<<<dim3(64), dim3(256), 0, stream>>>(W2, w2f);
        prep_node<<<dim3(25000), dim3(256), 0, stream>>>(node_emb, nbf);
        edge_mlp<true, false><<<dim3(2048), dim3(256), 0, stream>>>(
            node_emb, nbf, edge_index, edge_sel, W1, b1, W2, b2, w1f, w2f, out);
    } else if (ws_size >= NEED_B) {
        unsigned short* w2f = w1f + 32768;
        prep_w2<<<dim3(64), dim3(256), 0, stream>>>(W2, w2f);
        edge_mlp<false, false><<<dim3(2048), dim3(256), 0, stream>>>(
            node_emb, nullptr, edge_index, edge_sel, W1, b1, W2, b2, w1f, w2f, out);
    } else {
        edge_mlp<false, true><<<dim3(2048), dim3(256), 0, stream>>>(
            node_emb, nullptr, edge_index, edge_sel, W1, b1, W2, b2, w1f, nullptr, out);
    }
}

// Round 3
// 925.023 us; speedup vs baseline: 2.6213x; 2.6213x over previous
//
#include <hip/hip_runtime.h>
#include <stdint.h>

// Problem constants (EdgeEncoder_28071906247258)
#define BB 4
#define NN 100000
#define DD 128
#define EE 262144   // 2^18 edges per batch
#define HH 128
#define OO 128

typedef __attribute__((ext_vector_type(4))) float f32x4;
typedef __attribute__((ext_vector_type(8))) __bf16 bf16x8;
typedef __attribute__((ext_vector_type(8))) unsigned short u16x8;

static __device__ __forceinline__ unsigned short f2bf(float f) {
    union { float f; unsigned u; } v; v.f = f;
    return (unsigned short)((v.u + 0x7fffu + ((v.u >> 16) & 1u)) >> 16);  // RNE
}

// ---------------------------------------------------------------------------
// Prep: swizzle W1 rows 0..255 (fp32 [257][128]) into bf16 B-fragment order:
//   frag(kt,nt): lane holds W[k = kt*32 + (lane>>4)*8 + j][n = nt*16 + (lane&15)]
//   flat ushort index = ((kt*8+nt)*64 + lane)*8 + j
// ---------------------------------------------------------------------------
__global__ __launch_bounds__(256) void prep_w1(const float* __restrict__ W1,
                                               unsigned short* __restrict__ w1f) {
    int t = blockIdx.x * 256 + threadIdx.x;          // grid exact: 128*256 = 32768
    int k = t >> 7, n = t & 127;
    int f = ((((k >> 5) * 8 + (n >> 4)) * 64) + ((k >> 3) & 3) * 16 + (n & 15)) * 8 + (k & 7);
    w1f[f] = f2bf(W1[t]);
}

// W2 fragments with permuted k-axis: k2 = (k&15)*8 + (k>>4). The h-tile is
// stored in the same permuted order, so layer 2 computes the identical dot
// product with contiguous-per-lane LDS writes (ds_write_b128).
__global__ __launch_bounds__(256) void prep_w2(const float* __restrict__ W2,
                                               unsigned short* __restrict__ w2f) {
    int t = blockIdx.x * 256 + threadIdx.x;          // grid exact: 64*256 = 16384
    int k = t >> 7, n = t & 127;
    int k2 = (k & 15) * 8 + (k >> 4);
    int f = ((((k2 >> 5) * 8 + (n >> 4)) * 64) + ((k2 >> 3) & 3) * 16 + (n & 15)) * 8 + (k2 & 7);
    w2f[f] = f2bf(W2[t]);
}

// node_emb fp32 -> bf16 (same RNE conversion the hot loop used to do per-gather)
__global__ __launch_bounds__(256) void prep_node(const float* __restrict__ ne,
                                                 unsigned short* __restrict__ nb) {
    size_t t = (size_t)blockIdx.x * 256 + threadIdx.x;   // grid exact: 25000*256 = 6.4M
    const f32x4* s = (const f32x4*)ne + (t << 1);
    f32x4 a = s[0], b = s[1];
    u16x8 o;
    o[0] = f2bf(a[0]); o[1] = f2bf(a[1]); o[2] = f2bf(a[2]); o[3] = f2bf(a[3]);
    o[4] = f2bf(b[0]); o[5] = f2bf(b[1]); o[6] = f2bf(b[2]); o[7] = f2bf(b[3]);
    *((u16x8*)nb + t) = o;
}

// ---------------------------------------------------------------------------
// Fused edge MLP. Block = 256 threads = 4 waves; each wave owns one 32-edge
// tile (2 M-tiles of 16). A-fragments are loaded just-in-time per kt (small
// register window; compiler hoists ahead within the launch-bounds budget).
// All LDS is per-wave private -> no __syncthreads on the main path.
// Output stores go through a per-wave LDS bounce so each global store is a
// fully-contiguous 1 KB dwordx4 (2 address segments) instead of 64 scalar
// stores scattering 16 segments each (TA-pipe saturation was the round-1
// bottleneck: all BW/compute counters <40% with 25K-cycle wave lifetimes).
//   BF16N : gather pre-converted bf16 node rows
//   W2LDS : last-resort tiny-workspace path (stage W2 frags in LDS)
// ---------------------------------------------------------------------------
template<bool BF16N, bool W2LDS>
__global__ __launch_bounds__(256, 3) void edge_mlp(
    const float* __restrict__ node_emb,
    const unsigned short* __restrict__ node_bf,
    const int* __restrict__ edge_index,
    const float* __restrict__ edge_sel,
    const float* __restrict__ W1,
    const float* __restrict__ b1,
    const float* __restrict__ W2,
    const float* __restrict__ b2,
    const unsigned short* __restrict__ w1f,
    const unsigned short* __restrict__ w2f,
    float* __restrict__ out)
{
    // Per-wave scratch: h tiles (2 q-tiles, row stride 136 u16) = 8704 B/wave.
    // The same 8704 B are later reused as the f32 store-bounce buffer
    // (16 rows x 132 f32 = 8448 B <= 8704).
    __shared__ unsigned short hst[4][2][16 * 136];
    __shared__ unsigned short w2s[W2LDS ? 16384 : 1];

    const int tid = threadIdx.x;

    if constexpr (W2LDS) {
        for (int s = tid; s < 16384; s += 256) {
            int k = s >> 7, n = s & 127;
            int k2 = (k & 15) * 8 + (k >> 4);
            int f = ((((k2 >> 5) * 8 + (n >> 4)) * 64) + ((k2 >> 3) & 3) * 16 + (n & 15)) * 8 + (k2 & 7);
            w2s[f] = f2bf(W2[s]);
        }
        __syncthreads();
    }

    const int lane = tid & 63;
    const int wv = tid >> 6;
    const int nl = lane & 15;     // A-row lane / output-col lane
    const int quad = lane >> 4;   // 0..3

    // Per-lane epilogue constants: col = nt*16 + nl
    float b1v[8], w1cv[8], b2v[8];
#pragma unroll
    for (int nt = 0; nt < 8; ++nt) {
        b1v[nt] = b1[nt * 16 + nl];
        w1cv[nt] = W1[256 * 128 + nt * 16 + nl];  // W1 row 256 = sel weights
        b2v[nt] = b2[nt * 16 + nl];
    }

    const int eb = blockIdx.x * 128 + wv * 32;  // wave's 32-edge tile base
    const unsigned nbase = (unsigned)(eb >> 18) * (NN * DD);

    // Gather row offsets (element indices): lane's A-row edge = eb + mt*16 + nl
    unsigned ou[2], ov[2];
#pragma unroll
    for (int mt = 0; mt < 2; ++mt) {
        int e = eb + mt * 16 + nl;
        int2 p = ((const int2*)edge_index)[e];
        int iu = min(max(p.x, 0), NN - 1);
        int iv = min(max(p.y, 0), NN - 1);
        ou[mt] = nbase + (unsigned)iu * DD + quad * 8;
        ov[mt] = nbase + (unsigned)iv * DD + quad * 8;
    }

    // sel values for this lane's C-layout rows (edge = eb + q*16 + quad*4 + i)
    f32x4 sel[2];
    sel[0] = *(const f32x4*)(edge_sel + eb + quad * 4);
    sel[1] = *(const f32x4*)(edge_sel + eb + 16 + quad * 4);

    // ---- Layer 1: acc[mt][nt] = X[32x256] * W1[256x128] + b1 (bias in C-init)
    f32x4 acc[2][8];
#pragma unroll
    for (int mt = 0; mt < 2; ++mt)
#pragma unroll
        for (int nt = 0; nt < 8; ++nt)
            acc[mt][nt] = f32x4{b1v[nt], b1v[nt], b1v[nt], b1v[nt]};

    const bf16x8* w1b = (const bf16x8*)w1f;
#pragma unroll
    for (int kt = 0; kt < 8; ++kt) {
        bf16x8 af0, af1;
        if constexpr (BF16N) {
            af0 = *(const bf16x8*)(node_bf + ((kt < 4) ? ou[0] : ov[0]) + (kt & 3) * 32);
            af1 = *(const bf16x8*)(node_bf + ((kt < 4) ? ou[1] : ov[1]) + (kt & 3) * 32);
        } else {
#pragma unroll
            for (int mt = 0; mt < 2; ++mt) {
                unsigned o = ((kt < 4) ? ou[mt] : ov[mt]) + (kt & 3) * 32;
                f32x4 x0 = *(const f32x4*)(node_emb + o);
                f32x4 x1 = *(const f32x4*)(node_emb + o + 4);
                bf16x8 a;
                a[0] = (__bf16)x0[0]; a[1] = (__bf16)x0[1];
                a[2] = (__bf16)x0[2]; a[3] = (__bf16)x0[3];
                a[4] = (__bf16)x1[0]; a[5] = (__bf16)x1[1];
                a[6] = (__bf16)x1[2]; a[7] = (__bf16)x1[3];
                if (mt == 0) af0 = a; else af1 = a;
            }
        }
#pragma unroll
        for (int nt = 0; nt < 8; ++nt) {
            bf16x8 bf = w1b[(kt * 8 + nt) * 64 + lane];
            acc[0][nt] = __builtin_amdgcn_mfma_f32_16x16x32_bf16(af0, bf, acc[0][nt], 0, 0, 0);
            acc[1][nt] = __builtin_amdgcn_mfma_f32_16x16x32_bf16(af1, bf, acc[1][nt], 0, 0, 0);
        }
    }

    // ---- Epilogue 1: h = relu(acc + sel*w1c), packed bf16x8 LDS write in
    // permuted-k layout (k' = nl*8 + nt matches prep_w2's k2 permutation).
    unsigned short* hw = &hst[wv][0][0];
#pragma unroll
    for (int q = 0; q < 2; ++q) {
#pragma unroll
        for (int i = 0; i < 4; ++i) {
            bf16x8 hv;
#pragma unroll
            for (int nt = 0; nt < 8; ++nt) {
                float h = fmaf(sel[q][i], w1cv[nt], acc[q][nt][i]);
                hv[nt] = (__bf16)fmaxf(h, 0.f);
            }
            *(bf16x8*)(hw + q * (16 * 136) + (quad * 4 + i) * 136 + nl * 8) = hv;
        }
    }

    // ---- Layer 2: a2 = h[32x128] * W2[128x128] + b2 (bias in C-init) ----
    f32x4 a2[2][8];
#pragma unroll
    for (int q = 0; q < 2; ++q)
#pragma unroll
        for (int nt = 0; nt < 8; ++nt)
            a2[q][nt] = f32x4{b2v[nt], b2v[nt], b2v[nt], b2v[nt]};

    const bf16x8* w2b = (const bf16x8*)(W2LDS ? (const unsigned short*)w2s : w2f);
#pragma unroll
    for (int kt2 = 0; kt2 < 4; ++kt2) {
        bf16x8 h0 = *(const bf16x8*)(hw + nl * 136 + kt2 * 32 + quad * 8);
        bf16x8 h1 = *(const bf16x8*)(hw + 16 * 136 + nl * 136 + kt2 * 32 + quad * 8);
#pragma unroll
        for (int nt = 0; nt < 8; ++nt) {
            bf16x8 bf = w2b[(kt2 * 8 + nt) * 64 + lane];
            a2[0][nt] = __builtin_amdgcn_mfma_f32_16x16x32_bf16(h0, bf, a2[0][nt], 0, 0, 0);
            a2[1][nt] = __builtin_amdgcn_mfma_f32_16x16x32_bf16(h1, bf, a2[1][nt], 0, 0, 0);
        }
    }

    // ---- Epilogue 2: relu -> per-wave LDS bounce -> coalesced 1 KB stores.
    // h tiles are fully consumed; reuse hst as f32 bounce buffer,
    // row stride 132 f32 (528 B: quad*528 % 128B -> 2-way banks, free).
    float* fb = (float*)hw;
    const int rl = lane >> 5;        // 0..1: row parity within store pair
    const int cl = lane & 31;        // 0..31: 16B chunk within the 512B row
#pragma unroll
    for (int q = 0; q < 2; ++q) {
#pragma unroll
        for (int nt = 0; nt < 8; ++nt)
#pragma unroll
            for (int i = 0; i < 4; ++i)
                fb[(quad * 4 + i) * 132 + nt * 16 + nl] = fmaxf(a2[q][nt][i], 0.f);
        // read back row-major, store 2 full 512 B rows per instr
#pragma unroll
        for (int r = 0; r < 8; ++r) {
            f32x4 v = *(const f32x4*)(fb + (2 * r + rl) * 132 + cl * 4);
            *(f32x4*)(out + (size_t)(eb + q * 16 + 2 * r + rl) * OO + cl * 4) = v;
        }
    }
}

extern "C" void kernel_launch(void* const* d_in, const int* in_sizes, int n_in,
                              void* d_out, int out_size, void* d_ws, size_t ws_size,
                              hipStream_t stream) {
    const float* node_emb  = (const float*)d_in[0];
    const int*   edge_index= (const int*)d_in[1];
    const float* edge_sel  = (const float*)d_in[2];
    const float* W1        = (const float*)d_in[3];
    const float* b1        = (const float*)d_in[4];
    const float* W2        = (const float*)d_in[5];
    const float* b2        = (const float*)d_in[6];
    float* out             = (float*)d_out;

    unsigned short* w1f = (unsigned short*)d_ws;              // 64 KB
    const size_t NODE_BYTES = (size_t)BB * NN * DD * 2;       // 102,400,000 B
    const size_t NEED_B = 65536 + 32768;                      // w1f + w2f
    const size_t NEED_A = NEED_B + NODE_BYTES;

    prep_w1<<<dim3(128), dim3(256), 0, stream>>>(W1, w1f);

    // 8192 blocks * 4 waves * 32 edges = 1,048,576 edges, exact
    if (ws_size >= NEED_A) {
        unsigned short* w2f = w1f + 32768;       // byte offset 65536
        unsigned short* nbf = w2f + 16384;       // byte offset 98304 (16B aligned)
        prep_w2<<<dim3(64), dim3(256), 0, stream>>>(W2, w2f);
        prep_node<<<dim3(25000), dim3(256), 0, stream>>>(node_emb, nbf);
        edge_mlp<true, false><<<dim3(8192), dim3(256), 0, stream>>>(
            node_emb, nbf, edge_index, edge_sel, W1, b1, W2, b2, w1f, w2f, out);
    } else if (ws_size >= NEED_B) {
        unsigned short* w2f = w1f + 32768;
        prep_w2<<<dim3(64), dim3(256), 0, stream>>>(W2, w2f);
        edge_mlp<false, false><<<dim3(8192), dim3(256), 0, stream>>>(
            node_emb, nullptr, edge_index, edge_sel, W1, b1, W2, b2, w1f, w2f, out);
    } else {
        edge_mlp<false, true><<<dim3(8192), dim3(256), 0, stream>>>(
            node_emb, nullptr, edge_index, edge_sel, W1, b1, W2, b2, w1f, nullptr, out);
    }
}